// Round 9
// baseline (81.657 us; speedup 1.0000x reference)
//
#include <hip/hip_runtime.h>
#include <hip/hip_bf16.h>

typedef __attribute__((ext_vector_type(4))) float f32x4;

static constexpr int NROW = 8192;
static constexpr int DDIM = 512;
static constexpr float INV_T = 10.0f;    // 1 / temperature
static constexpr float SHIFT = 70.0f;    // fixed logsumexp shift (logit max ~60)

__device__ __forceinline__ void gload_lds16(const void* gsrc, void* ldst) {
  __builtin_amdgcn_global_load_lds(
      (const __attribute__((address_space(1))) unsigned int*)gsrc,
      (__attribute__((address_space(3))) unsigned int*)ldst, 16, 0, 0);
}

// pack 4 floats into 4 fp8 e4m3 bytes (gfx950: OCP encoding)
__device__ __forceinline__ unsigned int pack_fp8x4(float x, float y, float z, float w) {
  unsigned int r = 0;
  r = __builtin_amdgcn_cvt_pk_fp8_f32(x, y, r, false);  // bytes 0,1
  r = __builtin_amdgcn_cvt_pk_fp8_f32(z, w, r, true);   // bytes 2,3
  return r;
}

// ---------- prep: normalize anchor rows, cast both operands to fp8 e4m3 ----------
__global__ void prep_kernel(const float* __restrict__ f0,
                            const float* __restrict__ f1,
                            unsigned int* __restrict__ A,   // [NROW][DDIM] fp8, as u32x128/row
                            unsigned int* __restrict__ B,
                            float* __restrict__ wsS) {
  int gid  = blockIdx.x * blockDim.x + threadIdx.x;
  if (gid <= NROW) wsS[gid] = 0.f;            // zero accumulators (incl. pos slot)
  int wid  = gid >> 6;                         // one wave per row
  int lane = threadIdx.x & 63;
  const float4* s0 = (const float4*)(f0 + (size_t)wid * (2 * DDIM));  // features[:,0,:]
  const float4* s1 = (const float4*)(f1 + (size_t)wid * (2 * DDIM));  // features1[:,0,:]
  float4 v0 = s0[lane], v1 = s0[lane + 64];
  float ss = v0.x * v0.x + v0.y * v0.y + v0.z * v0.z + v0.w * v0.w +
             v1.x * v1.x + v1.y * v1.y + v1.z * v1.z + v1.w * v1.w;
#pragma unroll
  for (int m = 1; m < 64; m <<= 1) ss += __shfl_xor(ss, m);
  float rn = rsqrtf(ss);
  float4 w0 = s1[lane], w1 = s1[lane + 64];
  A[wid * 128 + lane]      = pack_fp8x4(v0.x * rn, v0.y * rn, v0.z * rn, v0.w * rn);
  A[wid * 128 + 64 + lane] = pack_fp8x4(v1.x * rn, v1.y * rn, v1.z * rn, v1.w * rn);
  B[wid * 128 + lane]      = pack_fp8x4(w0.x, w0.y, w0.z, w0.w);
  B[wid * 128 + 64 + lane] = pack_fp8x4(w1.x, w1.y, w1.z, w1.w);
}

// ---------- fused S = A.B^T / T with fixed-shift LSE accumulation (fp8) ----------
// grid 256 = 32 row panels (BM=256: 8 waves x 32 rows) x 8 column splits.
// LDS double-buffer (2x32 KiB, gload_lds with source-side XOR swizzle) AND
// accumulator double-buffer: EPILOGUE(t-1) is independent of MFMA(t), written
// adjacent so the scheduler fills MFMA's lgkm waits with epilogue VALU/trans —
// the exp phase no longer idles the matrix pipe (T15 pattern).
__global__ __launch_bounds__(512, 2) void sim_lse_kernel(
    const unsigned char* __restrict__ Ag,
    const unsigned char* __restrict__ Bg,
    float* __restrict__ wsS, float* __restrict__ wsPos) {
  __shared__ __align__(16) char bufA[64 * 512];   // 32 KiB, tiles 0,2,4,...
  __shared__ __align__(16) char bufB[64 * 512];   // 32 KiB, tiles 1,3,5,...

  const int tid  = threadIdx.x;
  const int w    = tid >> 6;
  const int lane = tid & 63;
  const int g    = lane >> 4;                // k-group 0..3
  const int lr   = lane & 15;                // row-in-frag (A) / col-in-frag (B,D)

  const int p  = blockIdx.x >> 3;            // row panel 0..31
  const int cs = blockIdx.x & 7;             // column split 0..7
  const int r0 = p * 256 + w * 32;           // this wave's first row
  const int c0 = cs * 1024;                  // first column of this split

  // staging: wave w stages row-pairs pr = it*8+w; lane covers 16 B of row
  // n = 2*pr + (lane>>5); source byte = ((lane&31)<<4) ^ ((n&7)<<4) with
  // (n&7) = (2w + (lane>>5)) & 7 -> per-thread constant swizzle.
  const int hi      = lane >> 5;
  const int stg_off = ((lane & 31) << 4) ^ (((2 * w + hi) & 7) << 4);
  const int stg_row = hi;

  // A fragments -> registers: a[i][ks] = 8 fp8 of A[r0+i*16+lr][ks*32 + g*8 .. +8)
  long a[2][16];
#pragma unroll
  for (int i = 0; i < 2; i++) {
    const char* arow = (const char*)Ag + (size_t)(r0 + i * 16 + lr) * DDIM + g * 8;
#pragma unroll
    for (int ks = 0; ks < 16; ks++)
      a[i][ks] = *(const long*)(arow + ks * 32);
  }

  float sums[2][4];
#pragma unroll
  for (int i = 0; i < 2; i++)
#pragma unroll
    for (int r = 0; r < 4; r++) sums[i][r] = 0.f;
  float pos_sum = 0.f;

  f32x4 acc0[2][4], acc1[2][4];              // double-buffered accumulators

#define STAGE(BUF, T)                                                          \
  {                                                                            \
    const char* gb = (const char*)Bg + (size_t)(c0 + (T) * 64) * DDIM;         \
    _Pragma("unroll")                                                          \
    for (int it = 0; it < 4; it++) {                                           \
      int pr = it * 8 + w;                                                     \
      gload_lds16(gb + (size_t)(2 * pr + stg_row) * DDIM + stg_off,            \
                  (char*)(BUF) + pr * 1024);                                   \
    }                                                                          \
  }

#define MFMA_TILE(BUF, ACC)                                                    \
  {                                                                            \
    _Pragma("unroll")                                                          \
    for (int i = 0; i < 2; i++)                                                \
      _Pragma("unroll")                                                        \
      for (int j = 0; j < 4; j++) ACC[i][j] = (f32x4){0.f, 0.f, 0.f, 0.f};     \
    _Pragma("unroll")                                                          \
    for (int ks = 0; ks < 16; ks++) {                                          \
      long bf[4];                                                              \
      _Pragma("unroll")                                                        \
      for (int j = 0; j < 4; j++) {                                            \
        int n = j * 16 + lr;                                                   \
        bf[j] = *(const long*)((const char*)(BUF) +                            \
                               ((n * 512 + ks * 32 + g * 8) ^ ((n & 7) << 4)));\
      }                                                                        \
      _Pragma("unroll")                                                        \
      for (int i = 0; i < 2; i++)                                              \
        _Pragma("unroll")                                                      \
        for (int j = 0; j < 4; j++)                                            \
          ACC[i][j] = __builtin_amdgcn_mfma_f32_16x16x32_fp8_fp8(              \
              a[i][ks], bf[j], ACC[i][j], 0, 0, 0);                            \
    }                                                                          \
  }

#define EPILOGUE(ACC, T)                                                       \
  {                                                                            \
    const int n0e = c0 + (T) * 64;                                             \
    const bool diag_tile = (r0 < n0e + 64) && (n0e < r0 + 32);                 \
    _Pragma("unroll")                                                          \
    for (int i = 0; i < 2; i++)                                                \
      _Pragma("unroll")                                                        \
      for (int j = 0; j < 4; j++)                                              \
        _Pragma("unroll")                                                      \
        for (int r = 0; r < 4; r++) {                                          \
          float av = ACC[i][j][r];                                             \
          if (diag_tile) {                                                     \
            int gr = r0 + i * 16 + g * 4 + r;                                  \
            int gc = n0e + j * 16 + lr;                                        \
            if (gr == gc) pos_sum += av * INV_T;                               \
          }                                                                    \
          sums[i][r] += __expf(fmaf(av, INV_T, -SHIFT));                       \
        }                                                                      \
  }

  STAGE(bufA, 0);
  __syncthreads();                            // tile 0 ready
  STAGE(bufB, 1);                             // async; lands under MFMA below
  MFMA_TILE(bufA, acc0);                      // tile 0 -> acc0
  __syncthreads();                            // tile 1 ready, bufA free

#pragma unroll 1
  for (int t = 1; t < 15; t += 2) {
    STAGE(bufA, t + 1);                       // stage even tile t+1
    MFMA_TILE(bufB, acc1);                    // tile t (odd) -> acc1
    EPILOGUE(acc0, t - 1);                    // finish tile t-1; co-schedules w/ MFMA
    __syncthreads();                          // bufA ready, bufB free
    STAGE(bufB, t + 2);                       // stage odd tile t+2 (t=13 -> 15)
    MFMA_TILE(bufA, acc0);                    // tile t+1 (even) -> acc0
    EPILOGUE(acc1, t);                        // finish tile t
    __syncthreads();                          // bufB ready, bufA free
  }
  // tiles 0..14 MFMA'd; bufB holds tile 15; acc0 holds tile 14 (unfinished)
  MFMA_TILE(bufB, acc1);                      // tile 15
  EPILOGUE(acc0, 14);
  EPILOGUE(acc1, 15);

#undef STAGE
#undef MFMA_TILE
#undef EPILOGUE

  // reduce over the 16 lanes holding the same rows (columns partition), commit
#pragma unroll
  for (int i = 0; i < 2; i++)
#pragma unroll
    for (int r = 0; r < 4; r++) {
      float s = sums[i][r];
      s += __shfl_xor(s, 1);
      s += __shfl_xor(s, 2);
      s += __shfl_xor(s, 4);
      s += __shfl_xor(s, 8);
      if (lr == 0) atomicAdd(&wsS[r0 + i * 16 + g * 4 + r], s);
    }
  if (pos_sum != 0.f) atomicAdd(wsPos, pos_sum);
}

// ---------- finalize: loss = mean(SHIFT + log(S_r)) - mean(pos) ----------
__global__ void finalize_kernel(const float* __restrict__ wsS,
                                const float* __restrict__ wsPos,
                                float* __restrict__ out) {
  __shared__ float red[16];
  float part = 0.f;
  for (int r = threadIdx.x; r < NROW; r += 1024)
    part += SHIFT + __logf(wsS[r]);
#pragma unroll
  for (int m = 1; m < 64; m <<= 1) part += __shfl_xor(part, m);
  if ((threadIdx.x & 63) == 0) red[threadIdx.x >> 6] = part;
  __syncthreads();
  if (threadIdx.x < 16) {
    float t = red[threadIdx.x];
#pragma unroll
    for (int m = 1; m < 16; m <<= 1) t += __shfl_xor(t, m);
    if (threadIdx.x == 0) out[0] = (t - wsPos[0]) / (float)NROW;
  }
}

extern "C" void kernel_launch(void* const* d_in, const int* in_sizes, int n_in,
                              void* d_out, int out_size, void* d_ws, size_t ws_size,
                              hipStream_t stream) {
  const float* f0 = (const float*)d_in[0];
  const float* f1 = (const float*)d_in[1];
  // d_in[2] (y) is unused by the reference computation.

  unsigned char* A = (unsigned char*)d_ws;                         // 4 MiB fp8
  unsigned char* B = A + (size_t)NROW * DDIM;                      // 4 MiB fp8
  float* wsS  = (float*)(B + (size_t)NROW * DDIM);
  float* wsPos = wsS + NROW;

  prep_kernel<<<NROW / 4, 256, 0, stream>>>(f0, f1, (unsigned int*)A,
                                            (unsigned int*)B, wsS);
  sim_lse_kernel<<<256, 512, 0, stream>>>(A, B, wsS, wsPos);
  finalize_kernel<<<1, 1024, 0, stream>>>(wsS, wsPos, (float*)d_out);
}